// Round 13
// baseline (123.805 us; speedup 1.0000x reference)
//
#include <hip/hip_runtime.h>
#include <hip/hip_bf16.h>
#include <hip/hip_fp16.h>
#include <math.h>

#define BB 8
#define HH 96
#define WW 96
#define HW 9216
#define BN_EPS 1e-5f

typedef _Float16 f16x2 __attribute__((ext_vector_type(2)));
typedef _Float16 f16x8 __attribute__((ext_vector_type(8)));
typedef float f32x4 __attribute__((ext_vector_type(4)));

union HU  { _Float16 h; unsigned short u; };
union UH2 { unsigned u; f16x2 h; };

// ---- workspace layout (bytes) ----
#define OFF_MO   0
#define SZ_MO    (BB*576*144*16)       // metaOFF: uint4 tap byte-offsets per (b,tile,px,k)
#define OFF_MW   (OFF_MO + SZ_MO)
#define SZ_MW    (BB*576*144*16)       // metaW4: uint4 packed f16-pair weights
#define OFF_XT   (OFF_MW + SZ_MW)
#define SZ_XT    (BB*HW*64*2)          // fp16 x transposed (B,H,W,C)
#define OFF_WB   (OFF_XT + SZ_XT)
#define SZ_WB    (64*576*2)            // wB[o][k*64+c] fp16 (main conv)
#define OFF_WO   (OFF_WB + SZ_WB)
#define SZ_WO    (32*576*2)            // wOff[oc][kk*64+c] fp16
#define OFF_BN   (OFF_WO + SZ_WO)
#define SZ_BN    (64*2*4)              // bnS[64], bnB[64]

// ---------------- prep: weight transposes + BN fold ----------------
__global__ __launch_bounds__(256) void prep_kernel(
    const float* __restrict__ weight, const float* __restrict__ offw,
    const float* __restrict__ modw,
    const float* __restrict__ bias, const float* __restrict__ gamma,
    const float* __restrict__ beta, const float* __restrict__ mean,
    const float* __restrict__ var,
    _Float16* __restrict__ wB, _Float16* __restrict__ wOff,
    float* __restrict__ bnS, float* __restrict__ bnB) {
  int tid = blockIdx.x * 256 + threadIdx.x;
  if (tid < 64 * 576) {
    int o = tid / 576, ck = tid % 576;
    int k = ck >> 6, c = ck & 63;                // ck = k*64 + c
    wB[tid] = (_Float16)weight[o * 576 + c * 9 + k];
  }
  int t2 = tid - 64 * 576;
  if (t2 >= 0 && t2 < 32 * 576) {
    int oc = t2 / 576, kcol = t2 % 576;
    int kk = kcol >> 6, c = kcol & 63;           // kcol = kk*64 + c
    float v = 0.f;
    if (oc < 18)      v = offw[(oc * 64 + c) * 9 + kk];
    else if (oc < 27) v = modw[((oc - 18) * 64 + c) * 9 + kk];
    wOff[t2] = (_Float16)v;
  }
  int t3 = tid - (64 * 576 + 32 * 576);
  if (t3 >= 0 && t3 < 64) {
    float inv = gamma[t3] * rsqrtf(var[t3] + BN_EPS);
    bnS[t3] = inv;
    bnB[t3] = (bias[t3] - mean[t3]) * inv + beta[t3];
  }
}

// ---------------- LDS-tiled transpose x -> (B,H,W,C) fp16 (XCD-swizzled) ----
__global__ __launch_bounds__(256) void transpose_x_kernel(
    const float* __restrict__ x, _Float16* __restrict__ xT) {
  __shared__ float tile[64][65];
  int tid = threadIdx.x;
  int b = blockIdx.x & 7;                        // image b stays on one XCD
  int hwb = (blockIdx.x >> 3) * 64;
  int col = tid & 63, g = tid >> 6;
  float r[16];
#pragma unroll
  for (int it = 0; it < 16; ++it)
    r[it] = x[(b * 64 + it * 4 + g) * HW + hwb + col]; // coalesced 256B
  __builtin_amdgcn_sched_barrier(0);
#pragma unroll
  for (int it = 0; it < 16; ++it)
    tile[it * 4 + g][col] = r[it];
  __syncthreads();
#pragma unroll
  for (int it = 0; it < 16; ++it) {
    int p = it * 4 + g;
    xT[(size_t)(b * HW + hwb + p) * 64 + col] = (_Float16)tile[col][p];
  }
}

__device__ __forceinline__ unsigned rep16(float w) {
  HU cv; cv.h = (_Float16)w;
  return 0x10001u * (unsigned)cv.u;
}

// ---------------- offset/mod conv via MFMA + fold into tile-ordered meta ----------------
__global__ __launch_bounds__(256, 8) void conv_offsets_kernel(
    const _Float16* __restrict__ xTh, const _Float16* __restrict__ wOff,
    const float* __restrict__ offb, const float* __restrict__ modb,
    uint4* __restrict__ metaOFF, uint4* __restrict__ metaW4) {
  __shared__ __attribute__((aligned(16))) _Float16 sN[3 * 34 * 70]; // stride-70 pad
  __shared__ float o_off[32 * 33];

  int tid = threadIdx.x;
  int lane = tid & 63;
  int wv = __builtin_amdgcn_readfirstlane(tid >> 6);

  int bi = blockIdx.x;                                  // 8b x 288 tiles
  int b = bi & 7, rem = bi >> 3;                        // XCD-swizzled
  int h = rem / 3, w0 = (rem % 3) * 32;

  // ---- stage 3 rows x 34 cols x 64 ch: batch-load to regs, then ds_write ----
  const _Float16* xb = xTh + (size_t)b * HW * 64;
  _Float16 sv[26];
#pragma unroll
  for (int i = 0; i < 26; ++i) {
    int p = wv + 4 * i;
    _Float16 v = (_Float16)0.f;
    if (p < 102) {
      int row = p / 34, col = p - row * 34;
      int y = h + row - 1, xx = w0 + col - 1;
      if ((y >= 0) && (y < HH) && (xx >= 0) && (xx < WW))
        v = xb[(size_t)(y * WW + xx) * 64 + lane];
    }
    sv[i] = v;
  }
  __builtin_amdgcn_sched_barrier(0);
#pragma unroll
  for (int i = 0; i < 26; ++i) {
    int p = wv + 4 * i;
    if (p < 102) {
      int row = p / 34, col = p - row * 34;
      sN[(row * 34 + col) * 70 + lane] = sv[i];
    }
  }
  __syncthreads();

  // ---- MFMA: C[32 px][32 oc], wave = (m-tile, n-tile) quadrant ----
  int r = lane & 15, g = lane >> 4;
  int mt = wv >> 1, nt = wv & 1;
  int px = mt * 16 + r;
  const _Float16* bp = wOff + (nt * 16 + r) * 576 + g * 8;
  f32x4 acc = {0.f, 0.f, 0.f, 0.f};
#pragma unroll
  for (int s = 0; s < 18; ++s) {
    int kk = s >> 1, ky = kk / 3, kx = kk - ky * 3;
    f16x8 a = *(const f16x8*)&sN[(ky * 34 + px + kx) * 70 + (s & 1) * 32 + g * 8];
    f16x8 bb = *(const f16x8*)(bp + s * 32);
    acc = __builtin_amdgcn_mfma_f32_16x16x32_f16(a, bb, acc, 0, 0, 0);
  }
#pragma unroll
  for (int j = 0; j < 4; ++j)
    o_off[(mt * 16 + g * 4 + j) * 33 + nt * 16 + r] = acc[j];
  __syncthreads();

  // ---- fold: sigmoid + bilinear weights + tap byte-offsets, tile-ordered ----
  for (int it = tid; it < 288; it += 256) {
    int pxx = it & 31, k = it >> 5;
    int ky = k / 3, kx = k - ky * 3;
    int w = w0 + pxx;

    float offy = o_off[pxx * 33 + 2 * k]     + offb[2 * k];
    float offx = o_off[pxx * 33 + 2 * k + 1] + offb[2 * k + 1];
    float mod  = 2.f / (1.f + __expf(-(o_off[pxx * 33 + 18 + k] + modb[k])));

    float py  = (float)(h - 1 + ky) + offy;
    float px_ = (float)(w - 1 + kx) + offx;
    float y0f = floorf(py), x0f = floorf(px_);
    float dy = py - y0f, dx = px_ - x0f;
    int y0 = (int)y0f, x0 = (int)x0f;
    int y1 = y0 + 1, x1 = x0 + 1;
    bool vy0 = (y0 >= 0) && (y0 < HH), vy1 = (y1 >= 0) && (y1 < HH);
    bool vx0 = (x0 >= 0) && (x0 < WW), vx1 = (x1 >= 0) && (x1 < WW);
    float w00 = (vy0 && vx0) ? (1.f - dy) * (1.f - dx) * mod : 0.f;
    float w01 = (vy0 && vx1) ? (1.f - dy) * dx * mod : 0.f;
    float w10 = (vy1 && vx0) ? dy * (1.f - dx) * mod : 0.f;
    float w11 = (vy1 && vx1) ? dy * dx * mod : 0.f;
    int y0c = min(max(y0, 0), HH - 1), y1c = min(max(y1, 0), HH - 1);
    int x0c = min(max(x0, 0), WW - 1), x1c = min(max(x1, 0), WW - 1);

    int tdcn = h * 6 + (w0 >> 4) + (pxx >> 4);          // dcn 16-px tile id
    int rec = ((b * 576 + tdcn) * 16 + (pxx & 15)) * 9 + k;
    metaOFF[rec] = make_uint4((unsigned)((y0c * WW + x0c) << 7),
                              (unsigned)((y0c * WW + x1c) << 7),
                              (unsigned)((y1c * WW + x0c) << 7),
                              (unsigned)((y1c * WW + x1c) << 7));
    metaW4[rec]  = make_uint4(rep16(w00), rep16(w01), rep16(w10), rep16(w11));
  }
}

// ---------------- fused deformable sample + MFMA GEMM + BN + ReLU ----------------
// Phase A v13: metadata staged to LDS (no s_loads on critical path); one
// dwordx2 gather covers all 4 taps of one k (9 gathers/px, was 20); 4-tap
// reduce via 2-stage packed-f16 shuffle butterfly (xor 8, xor 16).
__global__ __launch_bounds__(256, 6) void dcn_main_kernel(
    const _Float16* __restrict__ xT,
    const uint4* __restrict__ metaOFF, const uint4* __restrict__ metaW4,
    const _Float16* __restrict__ wB,
    const float* __restrict__ bnS, const float* __restrict__ bnB,
    float* __restrict__ out) {
  __shared__ __attribute__((aligned(16))) _Float16 s_A[16 * 584];
  __shared__ __attribute__((aligned(16))) uint4 m_off[144];
  __shared__ __attribute__((aligned(16))) uint4 m_w4[144];
  float* o_lds = (float*)s_A;                          // aliased after barrier

  int tid = threadIdx.x;
  int lane = tid & 63;
  int wv = __builtin_amdgcn_readfirstlane(tid >> 6);

  int bi = blockIdx.x;                                 // 8b x 576 tiles
  int b = bi & 7, t = bi >> 3;                         // XCD-swizzled: image->XCD
  int h = t / 6, w0 = (t - (t / 6) * 6) * 16;
  int hwrow = h * WW + w0;

  const unsigned char* xbc = (const unsigned char*)(xT + (size_t)b * HW * 64);

  // ---- stage this tile's 144 meta records (2 coalesced load groups) ----
  int base = (b * 576 + t) * 144;
  if (tid < 144) m_off[tid] = metaOFF[base + tid];
  int t2 = tid - 144;
  if (t2 >= 0) m_w4[t2] = metaW4[base + t2];           // records 0..111
  if (tid < 32) m_w4[112 + tid] = metaW4[base + 112 + tid];
  __syncthreads();

  const unsigned* offw32 = (const unsigned*)m_off;
  const unsigned* w4w32  = (const unsigned*)m_w4;
  int tsel = (lane >> 3) & 3;                          // tap index of this lane
  unsigned chB = (unsigned)(((lane >> 5) << 6) | ((lane & 7) << 3)); // byte off
  int c0 = ((lane >> 5) << 5) | ((lane & 7) << 2);     // first fp16 channel
  bool wlane = (lane & 24) == 0;                       // 16 writer lanes

#pragma unroll
  for (int px = 0; px < 4; ++px) {
    int pl = wv * 4 + px;
#pragma unroll
    for (int k = 0; k < 9; ++k) {
      int rec = (pl * 9 + k) * 4 + tsel;
      unsigned toff = offw32[rec];                     // ds_read, 4-addr bcast
      unsigned wsel = w4w32[rec];
      uint2 v = *(const uint2*)(xbc + toff + chB);     // 4 taps in one gather
      UH2 a0, a1, wz, r0, r1, s0, s1;
      a0.u = v.x; a1.u = v.y; wz.u = wsel;
      r0.h = a0.h * wz.h; r1.h = a1.h * wz.h;
      s0.u = __shfl_xor((int)r0.u, 8);                 // tap 0+1 / 2+3
      s1.u = __shfl_xor((int)r1.u, 8);
      r0.h += s0.h; r1.h += s1.h;
      s0.u = __shfl_xor((int)r0.u, 16);                // + cross pair
      s1.u = __shfl_xor((int)r1.u, 16);
      r0.h += s0.h; r1.h += s1.h;
      if (wlane)
        *(uint2*)&s_A[pl * 584 + k * 64 + c0] = make_uint2(r0.u, r1.u);
    }
  }
  __syncthreads();

  // ---- phase B: [16 x 576] x [576 x 64] fp16 MFMA, wave -> 16 out-channels ----
  int r = lane & 15, g = lane >> 4;
  const _Float16* arow = s_A + r * 584 + g * 8;
  const _Float16* bp = wB + (wv * 16 + r) * 576 + g * 8;
  f32x4 accA = {0.f, 0.f, 0.f, 0.f}, accB = {0.f, 0.f, 0.f, 0.f};
#pragma unroll 3
  for (int s = 0; s < 18; s += 2) {
    f16x8 a0 = *(const f16x8*)(arow + s * 32);
    f16x8 b0 = *(const f16x8*)(bp + s * 32);
    f16x8 a1 = *(const f16x8*)(arow + s * 32 + 32);
    f16x8 b1 = *(const f16x8*)(bp + s * 32 + 32);
    accA = __builtin_amdgcn_mfma_f32_16x16x32_f16(a0, b0, accA, 0, 0, 0);
    accB = __builtin_amdgcn_mfma_f32_16x16x32_f16(a1, b1, accB, 0, 0, 0);
  }

  // ---- epilogue: fused BN + ReLU, LDS transpose, coalesced store ----
  int o = wv * 16 + r;                                 // this lane's out channel
  float sc = bnS[o], sh = bnB[o];
  __syncthreads();                                     // all s_A reads done
#pragma unroll
  for (int j = 0; j < 4; ++j) {
    int px = g * 4 + j;                                // C row = (lane>>4)*4+j
    o_lds[o * 20 + px] = fmaxf((accA[j] + accB[j]) * sc + sh, 0.f);
  }
  __syncthreads();

  int oo = tid >> 2, q = tid & 3;
  float4 u = *(const float4*)&o_lds[oo * 20 + q * 4];
  *(float4*)(out + (size_t)(b * 64 + oo) * HW + hwrow + q * 4) = u;
}

extern "C" void kernel_launch(void* const* d_in, const int* in_sizes, int n_in,
                              void* d_out, int out_size, void* d_ws, size_t ws_size,
                              hipStream_t stream) {
  const float* x      = (const float*)d_in[0];
  const float* offw   = (const float*)d_in[1];
  const float* offb   = (const float*)d_in[2];
  const float* modw   = (const float*)d_in[3];
  const float* modb   = (const float*)d_in[4];
  const float* weight = (const float*)d_in[5];
  const float* bias   = (const float*)d_in[6];
  const float* gamma  = (const float*)d_in[7];
  const float* beta   = (const float*)d_in[8];
  const float* mean   = (const float*)d_in[9];
  const float* var    = (const float*)d_in[10];

  char* ws = (char*)d_ws;
  uint4*     metaOFF = (uint4*)(ws + OFF_MO);
  uint4*     metaW4  = (uint4*)(ws + OFF_MW);
  _Float16*  xTh     = (_Float16*)(ws + OFF_XT);
  _Float16*  wB      = (_Float16*)(ws + OFF_WB);
  _Float16*  wOff    = (_Float16*)(ws + OFF_WO);
  float*     bnS     = (float*)(ws + OFF_BN);
  float*     bnB     = bnS + 64;

  prep_kernel<<<217, 256, 0, stream>>>(weight, offw, modw, bias, gamma, beta,
                                       mean, var, wB, wOff, bnS, bnB);
  transpose_x_kernel<<<1152, 256, 0, stream>>>(x, xTh);
  conv_offsets_kernel<<<2304, 256, 0, stream>>>(xTh, wOff, offb, modb,
                                                metaOFF, metaW4);
  dcn_main_kernel<<<4608, 256, 0, stream>>>(xTh, metaOFF, metaW4, wB, bnS, bnB,
                                            (float*)d_out);
}